// Round 2
// 311.092 us; speedup vs baseline: 1.0120x; 1.0120x over previous
//
#include <hip/hip_runtime.h>
#include <hip/hip_bf16.h>

// Problem constants (T=2048, B=8, C=512, O=512, RD=64, NE=8, tau=1, commit=0.1)
// Round-8: k_moe restructured kk-outer(BK=64)/e-inner. A (raw bf16 x, NO resp
// scale) staged once per kk, fragments register-resident across all 9 experts;
// resp applied post-MFMA on f32 K=64 partials (ySum += s*t); bias expert (e=8)
// accumulates via MFMA C-in. Wave tile 128x32 -> B panels read exactly once.
// XOR chunk swizzle (c ^ (row&7)) on both A and B -> conflict-free b128 reads;
// B staged via gl_lds with inverse-swizzled global source, A packed via
// ds_write to swizzled slots (x f32 prefetched e==0, packed e==1).
// LDS bytes/FLOP 45.7 -> 19.6 (was LDS-pipe-bound at MfmaUtil 25.7%).
// Round-9: resubmit of round-8 (container-acquisition infra failure; kernel
// re-audited for deadlock/OOB — none found).
#define NROWS 16384
#define CC 512
#define OO 512
#define RDIM 64
#define NE 8
#define NEXP 9            // 8 experts + bias_w as expert 8 (scale 1.0)
#define COMMIT_SCALE 0.1f
#define LOG2PI_TERM 58.81206612509905f   // (RD/2)*log(2*pi*tau), tau=1

typedef __attribute__((ext_vector_type(8))) short short8;
typedef __attribute__((ext_vector_type(4))) float f32x4;

__device__ __forceinline__ unsigned short f2bf(float f) {
  unsigned int u = __float_as_uint(f);
  u += 0x7fffu + ((u >> 16) & 1u);   // round-to-nearest-even
  return (unsigned short)(u >> 16);
}
// truncating pack: [hi16(b) | hi16(a)]
__device__ __forceinline__ unsigned int pkt(float a, float b) {
  return (__float_as_uint(b) & 0xffff0000u) | (__float_as_uint(a) >> 16);
}

__device__ __forceinline__ void gl_lds16(const unsigned short* g, unsigned short* l) {
  __builtin_amdgcn_global_load_lds(
      (const __attribute__((address_space(1))) void*)g,
      (__attribute__((address_space(3))) void*)l, 16, 0, 0);
}

// ---------------------------------------------------------------------------
// Kernel 0: f32->bf16 copy of [pw_w ; bias_w] -> wb; transpose map_w -> wT4.
// ---------------------------------------------------------------------------
#define P4 524288u    // pw_w float4 count   (2097152 / 4)
#define B4 65536u     // bias_w float4 count (262144 / 4)
#define NCV ((P4 + B4) / 256u)        // 2304 convert blocks
#define TB 128u                        // 32768 map_w elems / 256

__global__ __launch_bounds__(256) void k_prep(
    const float* __restrict__ pw, const float* __restrict__ bw,
    const float* __restrict__ mw,
    unsigned short* __restrict__ wb, float* __restrict__ wT4)
{
  unsigned int b = blockIdx.x;
  if (b >= NCV) {   // map_w transpose: i indexes map_w[j*512+c]
    unsigned int i = (b - NCV) * 256 + threadIdx.x;
    unsigned int j = i >> 9, c = i & 511u;
    wT4[((c >> 2) << 8) + (j << 2) + (c & 3u)] = mw[i];
    return;
  }
  unsigned int i = b * 256 + threadIdx.x;   // float4 index into [pw|bw]
  const float* src = (i < P4) ? (pw + (size_t)i * 4)
                              : (bw + (size_t)(i - P4) * 4);
  unsigned short* dst = wb + (size_t)i * 4;
  float4 v = *(const float4*)src;
  ushort4 o;
  o.x = f2bf(v.x); o.y = f2bf(v.y); o.z = f2bf(v.z); o.w = f2bf(v.w);
  *(ushort4*)dst = o;
}

// ---------------------------------------------------------------------------
// Kernel 1: GMM responsibilities + loss (pure f32).
// ---------------------------------------------------------------------------
__global__ __launch_bounds__(256) void k_assign(
    const float* __restrict__ x,      // [N, C]
    const float* __restrict__ wT4,    // [C/4, 64, 4] transposed map_w
    const float* __restrict__ map_b,  // [RD]
    const float* __restrict__ cent,   // [NE, RD]
    const float* __restrict__ prior,  // [NE]
    float* __restrict__ resp_out,     // [N, NE] f32 (ws)
    float* __restrict__ loss_acc)     // [1] f32 (ws)
{
  __shared__ float lsum[4];
  const int tid  = threadIdx.x;
  const int wid  = tid >> 6;
  const int lane = tid & 63;
  const int row0 = blockIdx.x * 16 + wid * 4;

  const float* xr0 = x + (size_t)row0 * CC;
  float acc[4] = {0.f, 0.f, 0.f, 0.f};
  #pragma unroll 4
  for (int c0 = 0; c0 < CC; c0 += 4) {
    float4 wv = *(const float4*)&wT4[(c0 << 6) + (lane << 2)];  // coalesced
    #pragma unroll
    for (int r = 0; r < 4; ++r) {
      float4 xv = *(const float4*)(xr0 + r * CC + c0);          // wave-uniform
      acc[r] += xv.x * wv.x + xv.y * wv.y + xv.z * wv.z + xv.w * wv.w;
    }
  }
  const float mb = map_b[lane];
  float kk[4] = {acc[0] + mb, acc[1] + mb, acc[2] + mb, acc[3] + mb};

  float ce[8], c2[8], lp[8];
  #pragma unroll
  for (int e = 0; e < 8; ++e) {
    ce[e] = cent[e * RDIM + lane];
    float v = ce[e] * ce[e];
    #pragma unroll
    for (int off = 32; off; off >>= 1) v += __shfl_xor(v, off, 64);
    c2[e] = v;
    lp[e] = __logf(prior[e]);
  }

  float dsum = 0.f;
  #pragma unroll
  for (int r = 0; r < 4; ++r) {
    float k = kk[r];
    float v[9];
    v[0] = k * k;
    #pragma unroll
    for (int e = 0; e < 8; ++e) v[e + 1] = k * ce[e];
    #pragma unroll
    for (int off = 32; off; off >>= 1) {
      #pragma unroll
      for (int q = 0; q < 9; ++q) v[q] += __shfl_xor(v[q], off, 64);
    }
    float lr[8], mx = -3.4e38f;
    #pragma unroll
    for (int e = 0; e < 8; ++e) {
      float d2 = v[0] + c2[e] - 2.f * v[e + 1];
      lr[e] = -0.5f * d2 - LOG2PI_TERM + lp[e];
      mx = fmaxf(mx, lr[e]);
    }
    float s = 0.f;
    #pragma unroll
    for (int e = 0; e < 8; ++e) s += __expf(lr[e] - mx);
    float denom = mx + __logf(s);
    dsum += denom;
    float myv = 0.f;
    #pragma unroll
    for (int e = 0; e < 8; ++e) {
      float re = __expf(lr[e] - denom);
      myv = (lane == e) ? re : myv;
    }
    if (lane < 8) resp_out[(size_t)(row0 + r) * NE + lane] = myv;
  }
  if (lane == 0) lsum[wid] = dsum;
  __syncthreads();
  if (tid == 0) {
    float t = lsum[0] + lsum[1] + lsum[2] + lsum[3];
    atomicAdd(loss_acc, -COMMIT_SCALE * t);
  }
}

// ---------------------------------------------------------------------------
// Kernel 2: y[m,o] = sum_e resp[m,e] * sum_k x[m,k] W_e[o,k] + bias_b[o].
// 128x128 block tile, BK=64, kk-outer / e-inner. A = raw bf16(x), staged once
// per kk, fragments live in registers across the 9 experts. resp applied on
// the f32 K=64 partial (ySum += s*t); e==8 (bias_w) accumulates via MFMA C-in.
// Wave tile 128x32 (wn = wid*32). XOR chunk swizzle for conflict-free b128.
// ONE barrier per iteration; next B gl_lds issued right after it.
// ---------------------------------------------------------------------------
__global__ __launch_bounds__(256, 2) void k_moe(
    const float* __restrict__ x,             // [N, C] f32
    const unsigned short* __restrict__ wb,   // [9, O, C] bf16 (ws)
    const float* __restrict__ bb,            // [O] f32
    const float* __restrict__ resp,          // [N, NE] f32 (ws)
    const float* __restrict__ loss_acc,      // [1] f32 (ws)
    float* __restrict__ out)                 // [N*O + 1] f32
{
  __shared__ __align__(16) unsigned short aT[128 * 64];       // 16 KB, single buf
  __shared__ __align__(16) unsigned short bT[2][128 * 64];    // 32 KB dbuf
  __shared__ float sc[NE * 128];                              // 4 KB resp

  const int tid = threadIdx.x;
  const int m0 = blockIdx.x * 128;
  const int o0 = blockIdx.y * 128;
  const int lane = tid & 63;
  const int wid = tid >> 6;
  const int fr = lane & 15;
  const int fq = lane >> 4;

  // resp scales: sc[e][row] (only experts 0..7; e==8 needs no scale)
  for (int idx = tid; idx < 128 * NE; idx += 256) {
    int r = idx >> 3, e = idx & 7;
    sc[e * 128 + r] = resp[(size_t)(m0 + r) * NE + e];
  }

  // --- B staging map (gl_lds, inverse-swizzled global source) -------------
  // wave wid stages rows [wid*32, wid*32+32): call q covers rows +q*8+rl,
  // lane puts LDS chunk slot (l&7); fetches global chunk (l&7)^rl so that
  // LDS slot (row, c) holds global chunk c ^ (row&7).
  const int rl = lane >> 3;
  const int ch = lane & 7;
  const unsigned short* wb_t =
      wb + (size_t)(o0 + wid * 32 + rl) * CC + (ch ^ rl) * 8;

  // --- A pack map (ds_write to swizzled slots) ----------------------------
  const int ar = tid >> 1;          // row 0..127
  const int ah = tid & 1;           // chunk half: chunks ah*4 .. ah*4+3
  const float* xa = x + (size_t)(m0 + ar) * CC + ah * 32;

  // --- fragment read offsets (shorts) -------------------------------------
  // logical chunk h*4+fq at row r lives at slot (h*4+fq)^(r&7); r&7 == fr&7.
  const int s7 = fr & 7;
  const int ac0 = (fq ^ s7) * 8;    // h=0 chunk offset; h=1: ac0 ^ 32

  const f32x4 zero4 = {0.f, 0.f, 0.f, 0.f};
  f32x4 ySum[8][2];
  #pragma unroll
  for (int i = 0; i < 8; ++i) {
    ySum[i][0] = zero4; ySum[i][1] = zero4;
  }

  // --- prologue: pack A[kk=0]; gl_lds B[kk=0][e=0] into bT[0] -------------
  {
    const float4* xp = (const float4*)xa;
    #pragma unroll
    for (int q = 0; q < 4; ++q) {
      float4 f0 = xp[2 * q], f1 = xp[2 * q + 1];
      uint4 w;
      w.x = pkt(f0.x, f0.y); w.y = pkt(f0.z, f0.w);
      w.z = pkt(f1.x, f1.y); w.w = pkt(f1.z, f1.w);
      *(uint4*)&aT[ar * 64 + (((ah * 4 + q) ^ (ar & 7)) << 3)] = w;
    }
    #pragma unroll
    for (int q = 0; q < 4; ++q)
      gl_lds16(wb_t + q * 4096, &bT[0][wid * 2048 + q * 512]);
  }

  short8 af[16];     // A fragments for current kk, live across the 9 experts
  float4 xf[8];      // x f32 prefetch for next kk's A pack
  int cur = 0;

  #pragma unroll 1
  for (int kk = 0; kk < 8; ++kk) {
    #pragma unroll 1
    for (int e = 0; e < NEXP; ++e) {
      __syncthreads();   // drains prev-iter gl_lds/ds ops; bT[cur],aT ready

      // stage NEXT iteration's B (aged a full MFMA block at the next drain)
      if (e < 8 || kk < 7) {
        const int ne = (e < 8) ? e + 1 : 0;
        const int nk = (e < 8) ? kk : kk + 1;
        const unsigned short* bn = wb_t + ((size_t)ne << 18) + nk * 64;
        #pragma unroll
        for (int q = 0; q < 4; ++q)
          gl_lds16(bn + q * 4096, &bT[cur ^ 1][wid * 2048 + q * 512]);
      }

      if (e == 0) {
        // load A fragments for this kk (reused by all 9 experts)
        #pragma unroll
        for (int i = 0; i < 8; ++i) {
          const int rb = (i * 16 + fr) * 64;
          af[2 * i]     = *(const short8*)&aT[rb + ac0];
          af[2 * i + 1] = *(const short8*)&aT[rb + (ac0 ^ 32)];
        }
        if (kk < 7) {          // issue x f32 prefetch for kk+1
          const float4* xp = (const float4*)(xa + (kk + 1) * 64);
          #pragma unroll
          for (int q = 0; q < 8; ++q) xf[q] = xp[q];
        }
      } else if (e == 1 && kk < 7) {
        // pack A[kk+1] into aT (reads of aT finished at e==0, barrier since)
        #pragma unroll
        for (int q = 0; q < 4; ++q) {
          uint4 w;
          w.x = pkt(xf[2 * q].x,     xf[2 * q].y);
          w.y = pkt(xf[2 * q].z,     xf[2 * q].w);
          w.z = pkt(xf[2 * q + 1].x, xf[2 * q + 1].y);
          w.w = pkt(xf[2 * q + 1].z, xf[2 * q + 1].w);
          *(uint4*)&aT[ar * 64 + (((ah * 4 + q) ^ (ar & 7)) << 3)] = w;
        }
      }

      // B fragments for this (kk, e): wave's own 32-o panel, no duplication
      short8 bfv[4];
      const unsigned short* bc = &bT[cur][0];
      #pragma unroll
      for (int j = 0; j < 2; ++j) {
        const int rb = (wid * 32 + j * 16 + fr) * 64;
        bfv[2 * j]     = *(const short8*)&bc[rb + ac0];
        bfv[2 * j + 1] = *(const short8*)&bc[rb + (ac0 ^ 32)];
      }

      if (e < 8) {
        #pragma unroll
        for (int i = 0; i < 8; ++i) {
          const f32x4 s = *(const f32x4*)&sc[e * 128 + i * 16 + fq * 4];
          #pragma unroll
          for (int j = 0; j < 2; ++j) {
            f32x4 t = __builtin_amdgcn_mfma_f32_16x16x32_bf16(
                af[2 * i], bfv[2 * j], zero4, 0, 0, 0);
            t = __builtin_amdgcn_mfma_f32_16x16x32_bf16(
                af[2 * i + 1], bfv[2 * j + 1], t, 0, 0, 0);
            ySum[i][j] += s * t;
          }
        }
      } else {  // bias_w expert, scale 1.0: accumulate directly via C-in
        #pragma unroll
        for (int i = 0; i < 8; ++i) {
          #pragma unroll
          for (int j = 0; j < 2; ++j) {
            ySum[i][j] = __builtin_amdgcn_mfma_f32_16x16x32_bf16(
                af[2 * i], bfv[2 * j], ySum[i][j], 0, 0, 0);
            ySum[i][j] = __builtin_amdgcn_mfma_f32_16x16x32_bf16(
                af[2 * i + 1], bfv[2 * j + 1], ySum[i][j], 0, 0, 0);
          }
        }
      }
      cur ^= 1;
    }
  }

  // epilogue: + bias_b, store f32
  #pragma unroll
  for (int j = 0; j < 2; ++j) {
    const int o = o0 + wid * 32 + j * 16 + fr;
    const float bias = bb[o];
    #pragma unroll
    for (int i = 0; i < 8; ++i) {
      #pragma unroll
      for (int r = 0; r < 4; ++r) {
        int m = m0 + i * 16 + fq * 4 + r;
        out[(size_t)m * OO + o] = ySum[i][j][r] + bias;
      }
    }
  }

  if (blockIdx.x == 0 && blockIdx.y == 0 && tid == 0)
    out[(size_t)NROWS * OO] = loss_acc[0];
}

extern "C" void kernel_launch(void* const* d_in, const int* in_sizes, int n_in,
                              void* d_out, int out_size, void* d_ws, size_t ws_size,
                              hipStream_t stream) {
  const float* x     = (const float*)d_in[0];
  // d_in[1] = key_feat (ignored by forward)
  const float* map_w = (const float*)d_in[2];
  const float* map_b = (const float*)d_in[3];
  const float* cent  = (const float*)d_in[4];
  const float* prior = (const float*)d_in[5];
  const float* pw    = (const float*)d_in[6];
  const float* bw    = (const float*)d_in[7];
  const float* bb    = (const float*)d_in[8];
  float* out = (float*)d_out;

  char* wsp = (char*)d_ws;
  float* resp = (float*)wsp;                              // 524288 B
  float* loss = (float*)(wsp + 524288);                   // 16 B slot
  unsigned short* wb = (unsigned short*)(wsp + 524304);   // 4718592 B
  float* wT4 = (float*)(wsp + 524304 + 4718592);          // 131072 B

  hipMemsetAsync(loss, 0, sizeof(float), stream);
  k_prep<<<dim3(NCV + TB), dim3(256), 0, stream>>>(pw, bw, map_w, wb, wT4);
  k_assign<<<dim3(NROWS / 16), dim3(256), 0, stream>>>(x, wT4, map_b, cent, prior, resp, loss);
  dim3 grid(NROWS / 128, OO / 128);
  k_moe<<<grid, dim3(256), 0, stream>>>(x, wb, bb, resp, loss, out);
}